// Round 1
// baseline (3920.850 us; speedup 1.0000x reference)
//
#include <hip/hip_runtime.h>
#include <cstddef>

namespace {
constexpr int T_SEQ = 2048;
constexpr int D_IN  = 64;
constexpr int H1_   = 80;
constexpr int U_    = 65;
constexpr int NG    = 260;   // 4*U
constexpr int D2_   = 13;
constexpr int L_    = 8;
constexpr int KTOT  = 129;   // 64 + 65
constexpr int KPAD  = 140;   // padded k-extent per column (LDS row stride, 16B-aligned)
constexpr int INPAD = 136;   // cat-input row stride (16B-aligned, >= 132)
constexpr int NT    = 320;   // 5 waves
constexpr int B_    = 512;
constexpr int NCHUNK = 33;   // ceil(129/4): k reaches 131, pad weights are zero

__global__ __launch_bounds__(NT, 1)
void vae_lstm_fused(const float* __restrict__ x,
                    const float* __restrict__ eps,
                    const float* __restrict__ W1,
                    const float* __restrict__ b1,
                    const float* __restrict__ Wk,
                    const float* __restrict__ Wr,
                    const float* __restrict__ bl,
                    const float* __restrict__ W2,
                    const float* __restrict__ b2,
                    const float* __restrict__ Wm,
                    const float* __restrict__ bm,
                    const float* __restrict__ Wv,
                    const float* __restrict__ bv,
                    float* __restrict__ out)
{
    __shared__ float Wl[NG * KPAD];      // [col j][k]  (column-major per output col)
    __shared__ float inbuf[2 * INPAD];   // [row][k]: x_t in 0..63, h in 64..128, 0-pad 129..135
    __shared__ float zbuf[2 * NG];       // per-row gate pre-activations

    const int tid = threadIdx.x;
    const int r0  = blockIdx.x * 2;

    // ---- one-time init: fused weight matrix Wcat = [W1@Wk ; Wr], zero-padded ----
    for (int idx = tid; idx < NG * KPAD; idx += NT) {
        const int j = idx / KPAD;
        const int k = idx - j * KPAD;
        float v = 0.f;
        if (k < D_IN) {
            float s = 0.f;
            #pragma unroll 8
            for (int m = 0; m < H1_; ++m) s += W1[k * H1_ + m] * Wk[m * NG + j];
            v = s;
        } else if (k < KTOT) {
            v = Wr[(k - D_IN) * NG + j];
        }
        Wl[idx] = v;
    }
    float bcj = 0.f;   // fused bias: b1@Wk + bl
    if (tid < NG) {
        float s = bl[tid];
        #pragma unroll 8
        for (int m = 0; m < H1_; ++m) s += b1[m] * Wk[m * NG + tid];
        bcj = s;
    }
    if (tid < 2 * U_) {                         // h0 = 0
        const int r = tid < U_ ? 0 : 1;
        const int u = tid - r * U_;
        inbuf[r * INPAD + D_IN + u] = 0.f;
    }
    if (tid < 2 * (INPAD - KTOT)) {             // zero the k-pad region
        const int span = INPAD - KTOT;          // 7
        const int r = tid / span;
        const int kk = KTOT + (tid - r * span);
        inbuf[r * INPAD + kk] = 0.f;
    }

    float c_state = 0.f;                        // owned by threads tid < 130

    // prefetch x for t=0 (threads 0..127: 2 rows x 64 features)
    float xp = 0.f;
    const int xr = tid >> 6, xd = tid & 63;
    if (tid < 128) xp = x[((size_t)(r0 + xr) * T_SEQ + 0) * D_IN + xd];

    __syncthreads();

    for (int t = 0; t < T_SEQ; ++t) {
        if (tid < 128) inbuf[xr * INPAD + xd] = xp;
        __syncthreads();   // B1: x_t + h_{t-1} visible to all waves

        if (tid < 128 && t + 1 < T_SEQ)          // prefetch next step's x (hidden under compute)
            xp = x[((size_t)(r0 + xr) * T_SEQ + (t + 1)) * D_IN + xd];

        if (tid < NG) {
            const float4* wp = reinterpret_cast<const float4*>(&Wl[tid * KPAD]);
            const float4* a0 = reinterpret_cast<const float4*>(&inbuf[0]);
            const float4* a1 = reinterpret_cast<const float4*>(&inbuf[INPAD]);
            float4 s0 = make_float4(0.f, 0.f, 0.f, 0.f);
            float4 s1 = make_float4(0.f, 0.f, 0.f, 0.f);
            #pragma unroll
            for (int kc = 0; kc < NCHUNK; ++kc) {
                const float4 w = wp[kc];
                const float4 p = a0[kc];
                const float4 q = a1[kc];
                s0.x += w.x * p.x; s0.y += w.y * p.y; s0.z += w.z * p.z; s0.w += w.w * p.w;
                s1.x += w.x * q.x; s1.y += w.y * q.y; s1.z += w.z * q.z; s1.w += w.w * q.w;
            }
            zbuf[tid]      = (s0.x + s0.y) + (s0.z + s0.w) + bcj;
            zbuf[NG + tid] = (s1.x + s1.y) + (s1.z + s1.w) + bcj;
        }
        __syncthreads();   // B2: z visible

        if (tid < 2 * U_) {
            const int r = tid < U_ ? 0 : 1;
            const int u = tid - r * U_;
            const float* zr = &zbuf[r * NG];
            const float zi = zr[u];
            const float zf = zr[U_ + u];
            const float zg = zr[2 * U_ + u];
            const float zo = zr[3 * U_ + u];
            const float ig = 1.f / (1.f + __expf(-zi));
            const float fg = 1.f / (1.f + __expf(-zf));
            const float og = 1.f / (1.f + __expf(-zo));
            const float gt = tanhf(zg);
            c_state = fg * c_state + ig * gt;
            inbuf[r * INPAD + D_IN + u] = og * tanhf(c_state);
        }
        // no trailing barrier: next iteration's B1 orders h-writes before the k-loop reads,
        // and B2 already separated this iteration's z-reads from the next z-writes.
    }
    __syncthreads();

    // ---- tail: fc2 = h@W2 + b2 (2 x 13) ----
    if (tid < 2 * D2_) {
        const int r = tid / D2_, dd = tid - (tid / D2_) * D2_;
        float s = b2[dd];
        for (int u = 0; u < U_; ++u) s += inbuf[r * INPAD + D_IN + u] * W2[u * D2_ + dd];
        zbuf[r * NG + dd] = s;
    }
    __syncthreads();

    // ---- heads: z_mean, z_log_var, z ----
    if (tid < 2 * L_) {
        const int r = tid / L_, l = tid - (tid / L_) * L_;
        float zm = bm[l], zv = bv[l];
        for (int dd = 0; dd < D2_; ++dd) {
            const float f = zbuf[r * NG + dd];
            zm += f * Wm[dd * L_ + l];
            zv += f * Wv[dd * L_ + l];
        }
        const int row = r0 + r;
        const float e = eps[row * L_ + l];
        out[row * L_ + l]              = zm;
        out[B_ * L_ + row * L_ + l]    = zv;
        out[2 * B_ * L_ + row * L_ + l] = zm + expf(0.5f * zv) * e;
    }
}
} // namespace

extern "C" void kernel_launch(void* const* d_in, const int* in_sizes, int n_in,
                              void* d_out, int out_size, void* d_ws, size_t ws_size,
                              hipStream_t stream)
{
    const float* xin = (const float*)d_in[0];
    const float* eps = (const float*)d_in[1];
    const float* W1  = (const float*)d_in[2];
    const float* b1  = (const float*)d_in[3];
    const float* Wk  = (const float*)d_in[4];
    const float* Wr  = (const float*)d_in[5];
    const float* bl  = (const float*)d_in[6];
    const float* W2  = (const float*)d_in[7];
    const float* b2  = (const float*)d_in[8];
    const float* Wm  = (const float*)d_in[9];
    const float* bm  = (const float*)d_in[10];
    const float* Wv  = (const float*)d_in[11];
    const float* bv  = (const float*)d_in[12];
    float* out = (float*)d_out;

    hipLaunchKernelGGL(vae_lstm_fused, dim3(B_ / 2), dim3(NT), 0, stream,
                       xin, eps, W1, b1, Wk, Wr, bl, W2, b2, Wm, bm, Wv, bv, out);
}

// Round 6
// 1772.580 us; speedup vs baseline: 2.2119x; 2.2119x over previous
//
#include <hip/hip_runtime.h>
#include <cstddef>

namespace {
constexpr int T_SEQ = 2048;
constexpr int D_IN  = 64;
constexpr int H1_   = 80;
constexpr int U_    = 65;
constexpr int NG    = 260;    // 4*U
constexpr int D2_   = 13;
constexpr int L_    = 8;
constexpr int B_    = 512;
constexpr int NT    = 512;    // 8 waves
constexpr int KPADT = 160;    // padded K: 5 slices of 32 (64 x | 65 h | 31 zero)
constexpr int NPADT = 272;    // padded N: 17 tiles of 16
constexpr int IST   = 168;    // inb k-stride in shorts (2-way LDS aliasing = free)

typedef __attribute__((ext_vector_type(8))) short bf16x8;
typedef __attribute__((ext_vector_type(4))) float f32x4;

__device__ inline unsigned short f2bf(float f) {
    unsigned int u = __builtin_bit_cast(unsigned int, f);
    return (unsigned short)((u + 0x7FFFu + ((u >> 16) & 1u)) >> 16);  // RNE
}

__global__ __launch_bounds__(NT, 1)
void vae_lstm_mfma(const float* __restrict__ x,
                   const float* __restrict__ eps,
                   const float* __restrict__ W1,
                   const float* __restrict__ b1,
                   const float* __restrict__ Wk,
                   const float* __restrict__ Wr,
                   const float* __restrict__ bl,
                   const float* __restrict__ W2,
                   const float* __restrict__ b2,
                   const float* __restrict__ Wm,
                   const float* __restrict__ bm,
                   const float* __restrict__ Wv,
                   const float* __restrict__ bv,
                   float* __restrict__ out)
{
    // LDS: 87040 + 5376 + 2176 + 1040 + 520 = ~96 KB -> 1 block/CU
    __shared__ __align__(16) unsigned short Wb[NPADT * KPADT]; // Wcat^T: [n][k] bf16
    __shared__ __align__(16) unsigned short inb[16 * IST];     // A rows: [m][k] bf16 (rows 0,1 live)
    __shared__ float zbuf[2 * NPADT];                          // gate pre-activations
    __shared__ float bc[NG];                                   // fused bias b1@Wk + bl
    __shared__ float hbuf[2 * U_];                             // final h, fp32

    const int tid    = threadIdx.x;
    const int lane   = tid & 63;
    const int wv     = tid >> 6;
    const int lane16 = lane & 15;
    const int g4     = lane >> 4;            // k-group 0..3
    const int r0     = blockIdx.x * 2;

    // ---- init: Wcat = [W1@Wk ; Wr ; 0] as bf16, transposed [n][k] ----
    for (int idx = tid; idx < NPADT * KPADT; idx += NT) {
        const int n = idx / KPADT;
        const int k = idx - n * KPADT;
        float v = 0.f;
        if (n < NG) {
            if (k < D_IN) {
                float s = 0.f;
                #pragma unroll 8
                for (int m = 0; m < H1_; ++m) s += W1[k * H1_ + m] * Wk[m * NG + n];
                v = s;
            } else if (k < D_IN + U_) {
                v = Wr[(k - D_IN) * NG + n];
            }
        }
        Wb[idx] = f2bf(v);
    }
    if (tid < NG) {
        float s = bl[tid];
        #pragma unroll 8
        for (int m = 0; m < H1_; ++m) s += b1[m] * Wk[m * NG + tid];
        bc[tid] = s;
    }
    for (int idx = tid; idx < 16 * IST; idx += NT) inb[idx] = 0;  // h0=0, pads=0

    __syncthreads();  // S1: Wb/bc/inb visible

    // ---- load B-fragments into registers (permanent) ----
    const int tile0 = wv * 2, tile1 = wv * 2 + 1;
    const bool hasE = (wv == 7);             // wave 7 also owns tile 16
    bf16x8 wf0[5], wf1[5], wfe[5];
    #pragma unroll
    for (int s = 0; s < 5; ++s) {
        wf0[s] = *reinterpret_cast<const bf16x8*>(&Wb[(tile0 * 16 + lane16) * KPADT + 32 * s + 8 * g4]);
        wf1[s] = *reinterpret_cast<const bf16x8*>(&Wb[(tile1 * 16 + lane16) * KPADT + 32 * s + 8 * g4]);
    }
    if (hasE) {
        #pragma unroll
        for (int s = 0; s < 5; ++s)
            wfe[s] = *reinterpret_cast<const bf16x8*>(&Wb[(16 * 16 + lane16) * KPADT + 32 * s + 8 * g4]);
    }

    // ---- per-thread roles ----
    const int  aoff   = lane16 * IST + 8 * g4;          // A-frag base (shorts)
    const bool isGate = (tid < 2 * U_);
    const int  r_     = tid < U_ ? 0 : 1;
    const int  u_     = tid - r_ * U_;
    const int  zro    = r_ * NPADT;
    const int  hoff   = r_ * IST + D_IN + u_;
    float c_state = 0.f;

    const bool isX  = (wv == 3);                         // wave 3 stages x
    const int  xrow = (tid - 192) >> 5;                  // 0..1
    const int  xcp  = (tid - 192) & 31;                  // 0..31 (2 floats each)
    size_t xgbase = 0;
    if (isX) xgbase = ((size_t)(r0 + xrow) * T_SEQ) * D_IN + xcp * 2;

    if (isX) {  // stage x_0
        const float2 x0 = *reinterpret_cast<const float2*>(&x[xgbase]);
        const unsigned int pk = (unsigned int)f2bf(x0.x) | ((unsigned int)f2bf(x0.y) << 16);
        *reinterpret_cast<unsigned int*>(&inb[xrow * IST + xcp * 2]) = pk;
    }

    // ---- recurrent loop ----
    for (int t = 0; t < T_SEQ; ++t) {
        __syncthreads();  // B1: inb (x_t, h_{t-1}) ready

        float2 xp;
        const bool doX = isX && (t + 1 < T_SEQ);
        if (doX) xp = *reinterpret_cast<const float2*>(&x[xgbase + (size_t)(t + 1) * D_IN]);

        bf16x8 af[5];
        #pragma unroll
        for (int s = 0; s < 5; ++s)
            af[s] = *reinterpret_cast<const bf16x8*>(&inb[aoff + 32 * s]);

        f32x4 ac0 = {0.f, 0.f, 0.f, 0.f};
        f32x4 ac1 = {0.f, 0.f, 0.f, 0.f};
        f32x4 ace = {0.f, 0.f, 0.f, 0.f};
        #pragma unroll
        for (int s = 0; s < 5; ++s) {
            ac0 = __builtin_amdgcn_mfma_f32_16x16x32_bf16(af[s], wf0[s], ac0, 0, 0, 0);
            ac1 = __builtin_amdgcn_mfma_f32_16x16x32_bf16(af[s], wf1[s], ac1, 0, 0, 0);
            if (hasE)
                ace = __builtin_amdgcn_mfma_f32_16x16x32_bf16(af[s], wfe[s], ace, 0, 0, 0);
        }
        if (lane < 16) {  // rows 0,1 live in regs 0,1 of lanes 0..15
            zbuf[tile0 * 16 + lane]         = ac0[0];
            zbuf[NPADT + tile0 * 16 + lane] = ac0[1];
            zbuf[tile1 * 16 + lane]         = ac1[0];
            zbuf[NPADT + tile1 * 16 + lane] = ac1[1];
            if (hasE) {
                zbuf[256 + lane]         = ace[0];
                zbuf[NPADT + 256 + lane] = ace[1];
            }
        }
        __syncthreads();  // B2: z ready; all inb reads done

        if (isGate) {
            const float zi = zbuf[zro + u_]        + bc[u_];
            const float zf = zbuf[zro + U_ + u_]   + bc[U_ + u_];
            const float zg = zbuf[zro + 2*U_ + u_] + bc[2*U_ + u_];
            const float zo = zbuf[zro + 3*U_ + u_] + bc[3*U_ + u_];
            const float ig = 1.f / (1.f + __expf(-zi));
            const float fg = 1.f / (1.f + __expf(-zf));
            const float og = 1.f / (1.f + __expf(-zo));
            const float eg = __expf(2.f * zg);
            const float gt = (eg - 1.f) / (eg + 1.f);
            c_state = fg * c_state + ig * gt;
            const float ec = __expf(2.f * c_state);
            const float hc = og * ((ec - 1.f) / (ec + 1.f));
            inb[hoff] = f2bf(hc);
            if (t == T_SEQ - 1) hbuf[tid] = hc;
        }
        if (doX) {
            const unsigned int pk = (unsigned int)f2bf(xp.x) | ((unsigned int)f2bf(xp.y) << 16);
            *reinterpret_cast<unsigned int*>(&inb[xrow * IST + xcp * 2]) = pk;
        }
    }
    __syncthreads();

    // ---- tail: fc2 = h@W2 + b2 (fp32 h) ----
    if (tid < 2 * D2_) {
        const int r = tid / D2_, dd = tid - (tid / D2_) * D2_;
        float s = b2[dd];
        for (int u = 0; u < U_; ++u) s += hbuf[r * U_ + u] * W2[u * D2_ + dd];
        zbuf[r * NPADT + dd] = s;
    }
    __syncthreads();

    // ---- heads ----
    if (tid < 2 * L_) {
        const int r = tid / L_, l = tid - (tid / L_) * L_;
        float zm = bm[l], zv = bv[l];
        for (int dd = 0; dd < D2_; ++dd) {
            const float f = zbuf[r * NPADT + dd];
            zm += f * Wm[dd * L_ + l];
            zv += f * Wv[dd * L_ + l];
        }
        const int row = r0 + r;
        const float e = eps[row * L_ + l];
        out[row * L_ + l]               = zm;
        out[B_ * L_ + row * L_ + l]     = zv;
        out[2 * B_ * L_ + row * L_ + l] = zm + expf(0.5f * zv) * e;
    }
}
} // namespace

extern "C" void kernel_launch(void* const* d_in, const int* in_sizes, int n_in,
                              void* d_out, int out_size, void* d_ws, size_t ws_size,
                              hipStream_t stream)
{
    const float* xin = (const float*)d_in[0];
    const float* eps = (const float*)d_in[1];
    const float* W1  = (const float*)d_in[2];
    const float* b1  = (const float*)d_in[3];
    const float* Wk  = (const float*)d_in[4];
    const float* Wr  = (const float*)d_in[5];
    const float* bl  = (const float*)d_in[6];
    const float* W2  = (const float*)d_in[7];
    const float* b2  = (const float*)d_in[8];
    const float* Wm  = (const float*)d_in[9];
    const float* bm  = (const float*)d_in[10];
    const float* Wv  = (const float*)d_in[11];
    const float* bv  = (const float*)d_in[12];
    float* out = (float*)d_out;

    hipLaunchKernelGGL(vae_lstm_mfma, dim3(B_ / 2), dim3(NT), 0, stream,
                       xin, eps, W1, b1, Wk, Wr, bl, W2, b2, Wm, bm, Wv, bv, out);
}